// Round 19
// baseline (345.445 us; speedup 1.0000x reference)
//
#include <hip/hip_runtime.h>
#include <hip/hip_bf16.h>

#define NPIX 65536
#define CDIM 192
#define C2   384
#define HEADS 4
#define HD   48
#define PROW 258                    // padded row length (256 + 2)
#define XTROWS (PROW * PROW)        // 66564 padded pixel rows

typedef float f32x4 __attribute__((ext_vector_type(4)));
typedef short short8 __attribute__((ext_vector_type(8)));

__device__ __forceinline__ unsigned short f2bf(float x) {
  union { float f; unsigned u; } v; v.f = x;
  unsigned r = v.u + 0x7fff + ((v.u >> 16) & 1);   // RNE
  return (unsigned short)(r >> 16);
}
__device__ __forceinline__ float bf2f(unsigned short x) {
  union { unsigned u; float f; } v; v.u = ((unsigned)x) << 16;
  return v.f;
}
// chunk-XOR swizzle for 64B-stride rows (4 chunks/row)
__device__ __forceinline__ int f4(int r) { return (r ^ (r >> 2)) & 3; }

__device__ __forceinline__ void gload_lds16(const void* g, void* l) {
  __builtin_amdgcn_global_load_lds(
      (const __attribute__((address_space(1))) unsigned int*)g,
      (__attribute__((address_space(3))) unsigned int*)l, 16, 0, 0);
}

// ---------------------------------------------------------------------------
// cast weights to bf16 once
// ---------------------------------------------------------------------------
__global__ __launch_bounds__(256) void castw_kernel(
    const float* __restrict__ qkw, const float* __restrict__ vw,
    unsigned short* __restrict__ wqk, unsigned short* __restrict__ wv) {
  int i = blockIdx.x * 256 + threadIdx.x;
  if (i < C2 * CDIM) wqk[i] = f2bf(qkw[i]);
  if (i < CDIM * CDIM) wv[i] = f2bf(vw[i]);
}

// ---------------------------------------------------------------------------
// qk 1x1 conv as MFMA GEMM, BK=64: Out[oc][px] (bf16) = W[384][192]@X[192][px].
// 512 thr (8 waves), M=384 (x read once), N=128 px, 3 k-chunks of 64.
// Batch-merged: grid (512, 2), blockIdx.y = batch.
// ---------------------------------------------------------------------------
__global__ __launch_bounds__(512) void qk_mfma_kernel(
    const float* __restrict__ X0, const unsigned short* __restrict__ W,
    unsigned short* __restrict__ Out0) {
  const int b = blockIdx.y;
  const float* X = X0 + (size_t)b * CDIM * NPIX;
  unsigned short* Out = Out0 + (size_t)b * C2 * NPIX;
  const int px0 = blockIdx.x * 128;
  __shared__ __align__(16) char smem[67584];
  short* sA = (short*)smem;              // 384*64 (49152 B)
  short* sB = (short*)(smem + 49152);    // 128*72 (18432 B)
  const int t = threadIdx.x;
  const int lane = t & 63;
  const int wid = t >> 6;          // 0..7 -> oc rows wid*48..+47
  const int cpp = t & 31;          // channel pair 0..31 (64 ch per chunk)
  const int pg = t >> 5;           // 0..15 -> 8 px each
  const int l15 = lane & 15;
  const int l4 = lane >> 4;

  f32x4 acc[3][8];
#pragma unroll
  for (int mi = 0; mi < 3; ++mi)
#pragma unroll
    for (int ni = 0; ni < 8; ++ni) acc[mi][ni] = (f32x4){0.f, 0.f, 0.f, 0.f};

  for (int k0 = 0; k0 < CDIM; k0 += 64) {
    // A stage: 384 rows x 8 chunks = 3072 chunks, 6 issues x 512 lanes.
#pragma unroll
    for (int i = 0; i < 6; ++i) {
      int g = i * 512 + t;
      int row = g >> 3, ck = g & 7;
      gload_lds16(W + (size_t)row * CDIM + k0 + ((ck ^ (row & 7)) * 8),
                  (char*)sA + ((size_t)i * 512 + (t & ~63)) * 16);
    }
    // B stage: fused f32->bf16 transpose, 2 rows x 8 px per thread.
    {
      const float* xp = X + (size_t)(k0 + 2 * cpp) * NPIX + px0 + 8 * pg;
      float4 a0 = *(const float4*)xp;
      float4 a1 = *(const float4*)(xp + 4);
      float4 b0 = *(const float4*)(xp + NPIX);
      float4 b1 = *(const float4*)(xp + NPIX + 4);
      float av[8] = {a0.x, a0.y, a0.z, a0.w, a1.x, a1.y, a1.z, a1.w};
      float bv[8] = {b0.x, b0.y, b0.z, b0.w, b1.x, b1.y, b1.z, b1.w};
#pragma unroll
      for (int i = 0; i < 8; ++i) {
        unsigned d = (unsigned)f2bf(av[i]) | ((unsigned)f2bf(bv[i]) << 16);
        *(unsigned*)&sB[(8 * pg + i) * 72 + 2 * cpp] = d;
      }
    }
    asm volatile("s_waitcnt vmcnt(0)");
    __syncthreads();
#pragma unroll
    for (int kk = 0; kk < 2; ++kk) {
      short8 af[3], bf[8];
#pragma unroll
      for (int mi = 0; mi < 3; ++mi) {
        int row = wid * 48 + mi * 16 + l15;
        af[mi] = *(const short8*)&sA[row * 64 +
                                     (((kk * 4 + l4) ^ (row & 7)) * 8)];
      }
#pragma unroll
      for (int ni = 0; ni < 8; ++ni)
        bf[ni] = *(const short8*)&sB[(ni * 16 + l15) * 72 + (kk * 4 + l4) * 8];
#pragma unroll
      for (int mi = 0; mi < 3; ++mi)
#pragma unroll
        for (int ni = 0; ni < 8; ++ni)
          acc[mi][ni] = __builtin_amdgcn_mfma_f32_16x16x32_bf16(
              af[mi], bf[ni], acc[mi][ni], 0, 0, 0);
    }
    __syncthreads();
  }
  // Epilogue: per-wave zone (16 oc x 128 px, stride 136), short8 stores.
  short* zones = (short*)smem;
  short* zone = zones + wid * 2176;   // 8 * 2176 shorts = 34816 B <= 67584
#pragma unroll
  for (int mi = 0; mi < 3; ++mi) {
#pragma unroll
    for (int ni = 0; ni < 8; ++ni)
#pragma unroll
      for (int rg = 0; rg < 4; ++rg)
        zone[(l4 * 4 + rg) * 136 + ni * 16 + l15] =
            (short)f2bf(acc[mi][ni][rg]);
    asm volatile("s_waitcnt lgkmcnt(0)" ::: "memory");
    __builtin_amdgcn_sched_barrier(0);
#pragma unroll
    for (int it = 0; it < 4; ++it) {
      int e = it * 64 + lane;
      int ol = e >> 4, pxg = e & 15;
      short8 vv = *(const short8*)&zone[ol * 136 + pxg * 8];
      *(short8*)&Out[(size_t)(wid * 48 + mi * 16 + ol) * NPIX + px0 + pxg * 8] = vv;
    }
    asm volatile("s_waitcnt lgkmcnt(0)" ::: "memory");
    __builtin_amdgcn_sched_barrier(0);
  }
}

// ---------------------------------------------------------------------------
// FUSED independent-phase kernel: dwgram (512 blocks) | v_mfma (2048 blocks)
// | Xt border-zero (1028 blocks). All paths touch disjoint data (Xt no
// longer aliases qkb), 256 thr, LDS <= 38.4 KB -> 4 blocks/CU for all.
// Co-residency overlaps dwgram's latency stalls with v's MFMA work.
// ---------------------------------------------------------------------------
__global__ __launch_bounds__(256) void dwgram_v_kernel(
    const unsigned short* __restrict__ qkb0, const float* __restrict__ dw,
    float* __restrict__ gpart, float* __restrict__ ssp,
    const float* __restrict__ Y0, const unsigned short* __restrict__ Wv,
    unsigned short* __restrict__ Xt0) {
  __shared__ __align__(16) char smem[38400];
  const int t = threadIdx.x;
  const int lane = t & 63;
  const int wid = t >> 6;
  const int l15 = lane & 15;
  const int l4 = lane >> 4;

  if (blockIdx.x < 512) {
    // ================= dwgram path =================
    const int idx = blockIdx.x;
    const int braw = idx & 63;
    const int head = (idx >> 6) & 3;
    const int b = idx >> 8;
    const int bh = b * HEADS + head;
    const unsigned short* qkb = qkb0 + (size_t)b * C2 * NPIX;
    float* gpart_b = gpart + (size_t)bh * 64 * (HD * HD);
    float* ssp_b = ssp + (size_t)bh * 64 * 96;
    const int blk = (braw & 7) * 8 + (braw >> 3);   // XCD-contiguous band

    short* zone = (short*)smem + wid * (96 * 40);

    const int qrow0 = HD * head, krow0 = CDIM + HD * head;
    const int p0 = (lane & 1) * 16;
    const int c0 = (lane >> 1) * 3;

    float wr[3][9];
#pragma unroll
    for (int j = 0; j < 3; ++j) {
      int ch = c0 + j;
      int srow = (ch < HD) ? (qrow0 + ch) : (krow0 + ch - HD);
#pragma unroll
      for (int i = 0; i < 9; ++i) wr[j][i] = dw[srow * 9 + i];
    }

    f32x4 acc[3][3];
#pragma unroll
    for (int mi = 0; mi < 3; ++mi)
#pragma unroll
      for (int nj = 0; nj < 3; ++nj) acc[mi][nj] = (f32x4){0.f, 0.f, 0.f, 0.f};
    float ss[3] = {0.f, 0.f, 0.f};

    const int hr = blk * 4 + wid;       // this wave's image row
    for (int s = 0; s < 8; ++s) {
      const int cl = s * 32 + p0;
#pragma unroll
      for (int j = 0; j < 3; ++j) {
        int ch = c0 + j;
        int srow = (ch < HD) ? (qrow0 + ch) : (krow0 + ch - HD);
        const unsigned short* ip = qkb + (size_t)srow * NPIX;
        float win[3][18];
#pragma unroll
        for (int r = 0; r < 3; ++r) {
          int ir = hr - 1 + r;
          if ((unsigned)ir < 256u) {
            const unsigned short* rp = ip + ir * 256 + cl;
            short8 v0 = *(const short8*)rp;
            short8 v1 = *(const short8*)(rp + 8);
#pragma unroll
            for (int q = 0; q < 8; ++q) {
              win[r][1 + q] = bf2f((unsigned short)v0[q]);
              win[r][9 + q] = bf2f((unsigned short)v1[q]);
            }
            win[r][0]  = (cl > 0)        ? bf2f(rp[-1]) : 0.f;
            win[r][17] = (cl + 16 < 256) ? bf2f(rp[16]) : 0.f;
          } else {
#pragma unroll
            for (int q = 0; q < 18; ++q) win[r][q] = 0.f;
          }
        }
        unsigned pk[8];
#pragma unroll
        for (int p = 0; p < 16; ++p) {
          float sacc = 0.f;
#pragma unroll
          for (int r = 0; r < 3; ++r)
#pragma unroll
            for (int c = 0; c < 3; ++c) sacc += wr[j][r * 3 + c] * win[r][p + c];
          ss[j] += sacc * sacc;
          unsigned short bb = f2bf(sacc);
          if (p & 1) pk[p >> 1] |= ((unsigned)bb << 16);
          else       pk[p >> 1] = bb;
        }
        unsigned* zp = (unsigned*)&zone[ch * 40 + p0];
#pragma unroll
        for (int q = 0; q < 8; ++q) zp[q] = pk[q];
      }
      asm volatile("s_waitcnt lgkmcnt(0)" ::: "memory");
      __builtin_amdgcn_sched_barrier(0);
      short8 qf[3], kf[3];
#pragma unroll
      for (int mi = 0; mi < 3; ++mi)
        qf[mi] = *(const short8*)&zone[(mi * 16 + l15) * 40 + l4 * 8];
#pragma unroll
      for (int nj = 0; nj < 3; ++nj)
        kf[nj] = *(const short8*)&zone[(HD + nj * 16 + l15) * 40 + l4 * 8];
#pragma unroll
      for (int mi = 0; mi < 3; ++mi)
#pragma unroll
        for (int nj = 0; nj < 3; ++nj)
          acc[mi][nj] = __builtin_amdgcn_mfma_f32_16x16x32_bf16(
              qf[mi], kf[nj], acc[mi][nj], 0, 0, 0);
      asm volatile("s_waitcnt lgkmcnt(0)" ::: "memory");
      __builtin_amdgcn_sched_barrier(0);
    }
    // block-level reduce (overlay)
    __syncthreads();
    float* red   = (float*)smem;            // [4][2304]
    float* ssred = (float*)(smem + 36864);  // [4][96]
#pragma unroll
    for (int mi = 0; mi < 3; ++mi)
#pragma unroll
      for (int nj = 0; nj < 3; ++nj) {
        int kj = nj * 16 + l15;
#pragma unroll
        for (int rg = 0; rg < 4; ++rg) {
          int qi = mi * 16 + l4 * 4 + rg;
          red[wid * 2304 + qi * HD + kj] = acc[mi][nj][rg];
        }
      }
#pragma unroll
    for (int j = 0; j < 3; ++j) {
      float sj = ss[j] + __shfl_xor(ss[j], 1);
      if ((lane & 1) == 0) ssred[wid * 96 + c0 + j] = sj;
    }
    __syncthreads();
    float* gp = gpart_b + (size_t)blk * (HD * HD);
    for (int e = t; e < HD * HD; e += 256)
      gp[e] = red[e] + red[2304 + e] + red[4608 + e] + red[6912 + e];
    if (t < 96)
      ssp_b[(size_t)blk * 96 + t] =
          ssred[t] + ssred[96 + t] + ssred[192 + t] + ssred[288 + t];
    return;
  }

  if (blockIdx.x < 2560) {
    // ================= v_mfma path (T14 pipeline) =================
    const int idx = blockIdx.x - 512;
    const int b = idx >> 10;
    const float* Y = Y0 + (size_t)b * CDIM * NPIX;
    unsigned short* Xt = Xt0 + (size_t)b * XTROWS * CDIM;
    const int px0 = (idx & 1023) * 64;
    const int h = px0 >> 8;
    const int w0 = px0 & 255;
    const int cp = t & 15;
    const int pg = t >> 4;

    f32x4 acc[12];
#pragma unroll
    for (int ni = 0; ni < 12; ++ni) acc[ni] = (f32x4){0.f, 0.f, 0.f, 0.f};

#define SXB(p) ((short*)(smem + (p) * 5120))
#define SWB(p) ((short*)(smem + 10240 + (p) * 12288))
#define STAGE_W(k0_, p_)                                                     \
    {                                                                        \
      _Pragma("unroll")                                                      \
      for (int i = 0; i < 3; ++i) {                                          \
        int e = i * 256 + t;                                                 \
        int oc = e >> 2, kg = e & 3;                                         \
        gload_lds16(Wv + (size_t)oc * CDIM + (k0_) + (kg ^ f4(oc)) * 8,      \
                    (char*)SWB(p_) + ((size_t)i * 256 + (t & ~63)) * 16);    \
      }                                                                      \
    }
    float4 ya, yb;
#define LOAD_Y(k0_)                                                          \
    {                                                                        \
      const float* xp = Y + (size_t)((k0_) + 2 * cp) * NPIX + px0 + 4 * pg;  \
      ya = *(const float4*)xp;                                               \
      yb = *(const float4*)(xp + NPIX);                                      \
    }
#define WRITE_X(p_)                                                          \
    {                                                                        \
      float av[4] = {ya.x, ya.y, ya.z, ya.w};                                \
      float bv[4] = {yb.x, yb.y, yb.z, yb.w};                                \
      short* sx = SXB(p_);                                                   \
      _Pragma("unroll")                                                      \
      for (int i = 0; i < 4; ++i) {                                          \
        unsigned d = (unsigned)f2bf(av[i]) | ((unsigned)f2bf(bv[i]) << 16);  \
        *(unsigned*)&sx[(4 * pg + i) * 40 + 2 * cp] = d;                     \
      }                                                                      \
    }

    LOAD_Y(0);
    STAGE_W(0, 0);
    WRITE_X(0);
    asm volatile("s_waitcnt vmcnt(0)" ::: "memory");
    __syncthreads();

    for (int k = 0; k < 6; ++k) {
      const int p = k & 1;
      if (k < 5) {
        LOAD_Y((k + 1) * 32);
        STAGE_W((k + 1) * 32, p ^ 1);
      }
      {
        short* sx = SXB(p);
        short* sw = SWB(p);
        short8 af = *(const short8*)&sx[(wid * 16 + l15) * 40 + l4 * 8];
        short8 bf[12];
#pragma unroll
        for (int ni = 0; ni < 12; ++ni) {
          int row = ni * 16 + l15;
          bf[ni] = *(const short8*)&sw[row * 32 + (l4 ^ f4(row)) * 8];
        }
#pragma unroll
        for (int ni = 0; ni < 12; ++ni)
          acc[ni] = __builtin_amdgcn_mfma_f32_16x16x32_bf16(af, bf[ni], acc[ni],
                                                            0, 0, 0);
      }
      if (k < 5) WRITE_X(p ^ 1);
      asm volatile("s_waitcnt vmcnt(0)" ::: "memory");
      __syncthreads();
    }
#undef STAGE_W
#undef LOAD_Y
#undef WRITE_X
#undef SXB
#undef SWB

    // Epilogue: 2 oc-half passes of [16 px][104] zone.
    short* zone = (short*)(smem + 10240) + wid * (16 * 104);
#pragma unroll
    for (int oh = 0; oh < 2; ++oh) {
#pragma unroll
      for (int ni = 0; ni < 6; ++ni)
#pragma unroll
        for (int rg = 0; rg < 4; ++rg)
          zone[(l4 * 4 + rg) * 104 + ni * 16 + l15] =
              (short)f2bf(acc[oh * 6 + ni][rg]);
      asm volatile("s_waitcnt lgkmcnt(0)" ::: "memory");
      __builtin_amdgcn_sched_barrier(0);
#pragma unroll
      for (int it = 0; it < 3; ++it) {
        int e = it * 64 + lane;
        int pl = e / 12, cg = e % 12;
        short8 vv = *(const short8*)&zone[pl * 104 + cg * 8];
        size_t xrow = (size_t)(h + 1) * PROW + (w0 + wid * 16 + pl + 1);
        *(short8*)&Xt[xrow * CDIM + oh * 96 + cg * 8] = vv;
      }
      asm volatile("s_waitcnt lgkmcnt(0)" ::: "memory");
      __builtin_amdgcn_sched_barrier(0);
    }
    return;
  }

  // ================= Xt border-zero path =================
  {
    const int pos = blockIdx.x - 2560;    // 0..1027
    const int b = t >> 7;                 // 128 thr per batch
    const int tl = t & 127;
    unsigned short* Xt = Xt0 + (size_t)b * XTROWS * CDIM;
    size_t row;
    if (pos < 258) row = pos;
    else if (pos < 516) row = (size_t)257 * PROW + (pos - 258);
    else { int i = pos - 516; row = (size_t)(1 + (i >> 1)) * PROW + ((i & 1) ? 257 : 0); }
    unsigned* p = (unsigned*)(Xt + row * CDIM);
    if (tl < 96) p[tl] = 0;
  }
}

// ---------------------------------------------------------------------------
// parallel small-kernel chain: normred / gramred / softmax / buildM.
// ---------------------------------------------------------------------------
__global__ __launch_bounds__(64) void normred_kernel(
    const float* __restrict__ ssp, float* __restrict__ norms) {
  int idx = blockIdx.x;                 // 768 = 8 bh x 96 ch
  int bh = idx / 96, ch = idx % 96;
  int l = threadIdx.x;                  // 64
  float s = ssp[((size_t)bh * 64 + l) * 96 + ch];
#pragma unroll
  for (int off = 32; off; off >>= 1) s += __shfl_down(s, off);
  if (l == 0) {
    int b = bh >> 2, hh = bh & 3;
    int g = b * C2 + (ch < HD ? hh * HD + ch : CDIM + hh * HD + ch - HD);
    norms[g] = sqrtf(s);
  }
}

__global__ __launch_bounds__(256) void gramred_kernel(
    const float* __restrict__ part, float* __restrict__ logits) {
  int ij = blockIdx.x * 256 + threadIdx.x;
  int bh = blockIdx.y;
  if (ij >= HD * HD) return;
  const float* pp = part + (size_t)bh * 64 * (HD * HD);
  float s = 0.f;
  for (int sp = 0; sp < 64; ++sp) s += pp[(size_t)sp * (HD * HD) + ij];
  logits[(size_t)bh * (HD * HD) + ij] = s;
}

__global__ __launch_bounds__(64) void softmax_kernel(
    float* __restrict__ logits, const float* __restrict__ norms,
    const float* __restrict__ temperature) {
  int hh = blockIdx.x, b = blockIdx.y;
  int i = threadIdx.x;
  if (i >= HD) return;
  const float eps = 1e-12f;
  float temp = temperature[hh];
  float nq = fmaxf(norms[b * C2 + HD * hh + i], eps);
  float* row = logits + (((size_t)b * HEADS + hh) * HD + i) * HD;
  float vals[48];
  float mx = -1e30f;
#pragma unroll
  for (int j = 0; j < HD; ++j) {
    float nk = fmaxf(norms[b * C2 + CDIM + HD * hh + j], eps);
    float v = row[j] / (nq * nk) * temp;
    vals[j] = v;
    mx = fmaxf(mx, v);
  }
  float sum = 0.f;
#pragma unroll
  for (int j = 0; j < HD; ++j) {
    vals[j] = expf(vals[j] - mx);
    sum += vals[j];
  }
  float inv = 1.f / sum;
#pragma unroll
  for (int j = 0; j < HD; ++j) row[j] = vals[j] * inv;
}

__global__ __launch_bounds__(256) void buildM_kernel(
    const float* __restrict__ attn, const float* __restrict__ projw,
    float* __restrict__ M) {
  int idx = blockIdx.x * 256 + threadIdx.x;
  if (idx >= 2 * CDIM * CDIM) return;
  int d = idx % CDIM;
  int oc = (idx / CDIM) % CDIM;
  int b = idx / (CDIM * CDIM);
  int hh = d / HD, dd = d % HD;
  const float* arow = attn + ((size_t)b * HEADS + hh) * HD * HD;
  float s = 0.f;
#pragma unroll
  for (int c = 0; c < HD; ++c)
    s += projw[oc * CDIM + HD * hh + c] * arow[c * HD + dd];
  M[idx] = s;
}

// ---------------------------------------------------------------------------
// Wb[b][tap][oc][ic] (bf16) = sum_d M[b][oc][d] * Wv[d][ic][tap]
// ---------------------------------------------------------------------------
__global__ __launch_bounds__(256) void wtrans_kernel(
    const float* __restrict__ M, const float* __restrict__ Wv,
    unsigned short* __restrict__ Wb) {
  const int ocb = blockIdx.x * 4;
  const int ec0 = blockIdx.y * 432;
  const int b = blockIdx.z;
  __shared__ float sM[4][CDIM];
  for (int i = threadIdx.x; i < 4 * CDIM; i += 256)
    sM[i / CDIM][i % CDIM] =
        M[((size_t)b * CDIM + ocb + i / CDIM) * CDIM + (i % CDIM)];
  __syncthreads();
  for (int e = ec0 + threadIdx.x; e < ec0 + 432; e += 256) {
    float a0 = 0.f, a1 = 0.f, a2 = 0.f, a3 = 0.f;
#pragma unroll 4
    for (int d = 0; d < CDIM; ++d) {
      float wv = Wv[(size_t)d * (CDIM * 9) + e];
      a0 += sM[0][d] * wv; a1 += sM[1][d] * wv;
      a2 += sM[2][d] * wv; a3 += sM[3][d] * wv;
    }
    int ic = e / 9, tap = e % 9;
    size_t base = (((size_t)b * 9 + tap) * CDIM) * CDIM + ic;
    Wb[base + (size_t)(ocb + 0) * CDIM] = f2bf(a0);
    Wb[base + (size_t)(ocb + 1) * CDIM] = f2bf(a1);
    Wb[base + (size_t)(ocb + 2) * CDIM] = f2bf(a2);
    Wb[base + (size_t)(ocb + 3) * CDIM] = f2bf(a3);
  }
}

// ---------------------------------------------------------------------------
// MFMA conv3x3 v8: r-major dedup (18 stages), A consumed into registers,
// single-buffered sA: LDS 45.3 KB -> 3 blocks/CU. Batch-merged grid (768,2).
// ---------------------------------------------------------------------------
__global__ __launch_bounds__(256, 3) void conv3x3_mfma_kernel(
    const unsigned short* __restrict__ XtAll,  // [2][XTROWS][192] bf16
    const unsigned short* __restrict__ WbAll,  // [2][9][192][192] bf16
    float* __restrict__ outAll) {
  const int bb = blockIdx.y;
  const unsigned short* Xt = XtAll + (size_t)bb * XTROWS * CDIM;
  const unsigned short* Wb = WbAll + (size_t)bb * 9 * CDIM * CDIM;
  float* out = outAll + (size_t)bb * CDIM * NPIX;

  const int d = blockIdx.x;              // 768
  const int xcd = d & 7;
  const int j = d >> 3;                  // 0..95
  const int h = xcd * 32 + j / 3;        // image row 0..255
  const int oc0 = (j % 3) * 64;

  __shared__ __align__(16) short sA[3 * 64 * 32];      // 12,288 B (single buf)
  __shared__ __align__(16) short sB[2][258 * 32];      // 2 x 16,512 B

  const int t = threadIdx.x;
  const int lane = t & 63;
  const int wid = t >> 6;                // px quarter (64 px each)
  const int l15 = lane & 15;
  const int l4 = lane >> 4;

  f32x4 acc[4][4];
#pragma unroll
  for (int mi = 0; mi < 4; ++mi)
#pragma unroll
    for (int ni = 0; ni < 4; ++ni) acc[mi][ni] = (f32x4){0.f, 0.f, 0.f, 0.f};

  // A: 3 taps x 64 oc x 32 ic = 768 chunks = 3 uniform issues.
#define STAGE_A(sidx)                                                        \
  {                                                                          \
    const int ra_ = (sidx) / 6;                                              \
    const int ica_ = ((sidx) % 6) * 32;                                      \
    _Pragma("unroll")                                                        \
    for (int i = 0; i < 3; ++i) {                                            \
      int g = i * 256 + t;                                                   \
      int row = g >> 2, ck = g & 3;                                          \
      int tap = row >> 6, oc = row & 63;                                     \
      gload_lds16(Wb + ((size_t)(ra_ * 3 + tap) * CDIM + oc0 + oc) * CDIM +  \
                      ica_ + (ck ^ f4(row)) * 8,                             \
                  (char*)sA + (size_t)(i * 256 + wid * 64) * 16);            \
    }                                                                        \
  }
  // B: 258 px-rows x 32 ic = 1032 chunks = 4 full + 1 partial issue.
#define STAGE_B(sidx, bi)                                                    \
  {                                                                          \
    const int rs_ = (sidx) / 6;                                              \
    const int ics_ = ((sidx) % 6) * 32;                                      \
    const unsigned short* bsrc =                                             \
        Xt + (size_t)(h + rs_) * PROW * CDIM + ics_;                         \
    _Pragma("unroll")                                                        \
    for (int i = 0; i < 4; ++i) {                                            \
      int g = i * 256 + t;                                                   \
      int row = g >> 2, ck = g & 3;                                          \
      gload_lds16(bsrc + (size_t)row * CDIM + (ck ^ f4(row)) * 8,            \
                  (char*)sB[bi] + (size_t)(i * 256 + wid * 64) * 16);        \
    }                                                                        \
    { int g = 1024 + wid * 2 + lane;                                         \
      int row = g >> 2, ck = g & 3;                                          \
      if (lane < 2)                                                          \
        gload_lds16(bsrc + (size_t)row * CDIM + (ck ^ f4(row)) * 8,          \
                    (char*)sB[bi] + (size_t)(1024 + wid * 2) * 16);          \
    }                                                                        \
  }

  STAGE_A(0);
  STAGE_B(0, 0);
  asm volatile("s_waitcnt vmcnt(0)" ::: "memory");
  __syncthreads();

  int cur = 0;
  for (int s = 0; s < 18; ++s) {
    // consume A[s] into registers (12 ds_read_b128, conflict-free)
    short8 af_[3][4];
#pragma unroll
    for (int c = 0; c < 3; ++c)
#pragma unroll
      for (int mi = 0; mi < 4; ++mi) {
        int row = c * 64 + mi * 16 + l15;
        af_[c][mi] = *(const short8*)&sA[row * 32 + (l4 ^ f4(row)) * 8];
      }
    __syncthreads();                 // all waves done reading sA
    if (s < 17) {
      STAGE_A(s + 1);                // safe: sA consumed
      STAGE_B(s + 1, cur ^ 1);
    }
#pragma unroll
    for (int c = 0; c < 3; ++c) {
      short8 bf[4];
#pragma unroll
      for (int ni = 0; ni < 4; ++ni) {
        int row = wid * 64 + ni * 16 + l15 + c;   // padded px index
        bf[ni] = *(const short8*)&sB[cur][row * 32 + (l4 ^ f4(row)) * 8];
      }
#pragma unroll
      for (int mi = 0; mi < 4; ++mi)
#pragma unroll
        for (int ni = 0; ni < 4; ++ni)
          acc[mi][ni] = __builtin_amdgcn_mfma_f32_16x16x32_bf16(
              af_[c][mi], bf[ni], acc[mi][ni], 0, 0, 0);
    }
    asm volatile("s_waitcnt vmcnt(0)" ::: "memory");
    __syncthreads();                 // A[s+1], B[s+1] landed & visible
    cur ^= 1;
  }
#undef STAGE_A
#undef STAGE_B
  // D: col=lane&15 (px), row=(lane>>4)*4+reg (oc)
#pragma unroll
  for (int mi = 0; mi < 4; ++mi) {
    int ocl = oc0 + mi * 16 + l4 * 4;
#pragma unroll
    for (int ni = 0; ni < 4; ++ni) {
      int wloc = wid * 64 + ni * 16 + l15;
#pragma unroll
      for (int rg = 0; rg < 4; ++rg)
        out[(size_t)(ocl + rg) * NPIX + h * 256 + wloc] = acc[mi][ni][rg];
    }
  }
}

// ---------------------------------------------------------------------------
extern "C" void kernel_launch(void* const* d_in, const int* in_sizes, int n_in,
                              void* d_out, int out_size, void* d_ws, size_t ws_size,
                              hipStream_t stream) {
  const float* x          = (const float*)d_in[0];
  const float* y          = (const float*)d_in[1];
  const float* qk_w       = (const float*)d_in[2];
  const float* qk_dw_w    = (const float*)d_in[3];
  const float* v_w        = (const float*)d_in[4];
  const float* v_dw_w     = (const float*)d_in[5];
  const float* proj_w     = (const float*)d_in[6];
  const float* temperature= (const float*)d_in[7];
  float* out = (float*)d_out;

  // Workspace layout. Peak ~160 MB (ws ~400 MB). Xt now SEPARATE from qkb
  // (enables dwgram+v concurrency in one launch).
  unsigned short* qkb = (unsigned short*)d_ws;          // 2 x 384 x 65536 bf16
  unsigned short* XtA = qkb + (size_t)2 * C2 * NPIX;    // 2 x XTROWS x 192 bf16
  float* gpart  = (float*)(XtA + (size_t)2 * XTROWS * CDIM);  // [8][64][2304]
  float* ssp    = gpart + (size_t)8 * 64 * HD * HD;     // [8][64][96]
  float* norms  = ssp + (size_t)8 * 64 * 96;            // 768
  float* logits = norms + 768;                          // 4608
  float* M      = logits + 2 * HEADS * HD * HD;         // 73728
  unsigned short* wqk = (unsigned short*)(M + 2 * CDIM * CDIM);
  unsigned short* wv  = wqk + C2 * CDIM;
  unsigned short* Wb  = wv + CDIM * CDIM;               // 2*9*192*192 bf16
  size_t needB = (size_t)((char*)(Wb + (size_t)2 * 9 * CDIM * CDIM) - (char*)d_ws);
  if (ws_size < needB) return;

  castw_kernel<<<dim3(288), dim3(256), 0, stream>>>(qk_w, v_w, wqk, wv);

  // ---- qk 1x1 MFMA (batch-merged) ----
  qk_mfma_kernel<<<dim3(512, 2), dim3(512), 0, stream>>>(x, wqk, qkb);

  // ---- fused independent phases: dwgram | v_mfma | Xt border-zero ----
  dwgram_v_kernel<<<dim3(3588), dim3(256), 0, stream>>>(
      qkb, qk_dw_w, gpart, ssp, y, wv, XtA);

  // ---- small chain ----
  normred_kernel<<<dim3(768), dim3(64), 0, stream>>>(ssp, norms);
  gramred_kernel<<<dim3(9, 8), dim3(256), 0, stream>>>(gpart, logits);
  softmax_kernel<<<dim3(4, 2), dim3(64), 0, stream>>>(logits, norms, temperature);
  buildM_kernel<<<dim3(288), dim3(256), 0, stream>>>(logits, proj_w, M);
  wtrans_kernel<<<dim3(48, 4, 2), dim3(256), 0, stream>>>(M, v_dw_w, Wb);

  // ---- conv3x3 (batch-merged) ----
  conv3x3_mfma_kernel<<<dim3(768, 2), dim3(256), 0, stream>>>(XtA, Wb, out);
}

// Round 20
// 341.802 us; speedup vs baseline: 1.0107x; 1.0107x over previous
//
#include <hip/hip_runtime.h>
#include <hip/hip_bf16.h>

#define NPIX 65536
#define CDIM 192
#define C2   384
#define HEADS 4
#define HD   48
#define PROW 258                    // padded row length (256 + 2)
#define XTROWS (PROW * PROW)        // 66564 padded pixel rows

typedef float f32x4 __attribute__((ext_vector_type(4)));
typedef short short8 __attribute__((ext_vector_type(8)));

__device__ __forceinline__ unsigned short f2bf(float x) {
  union { float f; unsigned u; } v; v.f = x;
  unsigned r = v.u + 0x7fff + ((v.u >> 16) & 1);   // RNE
  return (unsigned short)(r >> 16);
}
__device__ __forceinline__ float bf2f(unsigned short x) {
  union { unsigned u; float f; } v; v.u = ((unsigned)x) << 16;
  return v.f;
}
// chunk-XOR swizzle for 64B-stride rows (4 chunks/row)
__device__ __forceinline__ int f4(int r) { return (r ^ (r >> 2)) & 3; }

__device__ __forceinline__ void gload_lds16(const void* g, void* l) {
  __builtin_amdgcn_global_load_lds(
      (const __attribute__((address_space(1))) unsigned int*)g,
      (__attribute__((address_space(3))) unsigned int*)l, 16, 0, 0);
}

// ---------------------------------------------------------------------------
// cast weights to bf16 once
// ---------------------------------------------------------------------------
__global__ __launch_bounds__(256) void castw_kernel(
    const float* __restrict__ qkw, const float* __restrict__ vw,
    unsigned short* __restrict__ wqk, unsigned short* __restrict__ wv) {
  int i = blockIdx.x * 256 + threadIdx.x;
  if (i < C2 * CDIM) wqk[i] = f2bf(qkw[i]);
  if (i < CDIM * CDIM) wv[i] = f2bf(vw[i]);
}

// ---------------------------------------------------------------------------
// qk 1x1 conv as MFMA GEMM, BK=64: Out[oc][px] (bf16) = W[384][192]@X[192][px].
// 512 thr (8 waves), M=384 (x read once), N=128 px, 3 k-chunks of 64.
// Batch-merged: grid (512, 2), blockIdx.y = batch.
// ---------------------------------------------------------------------------
__global__ __launch_bounds__(512) void qk_mfma_kernel(
    const float* __restrict__ X0, const unsigned short* __restrict__ W,
    unsigned short* __restrict__ Out0) {
  const int b = blockIdx.y;
  const float* X = X0 + (size_t)b * CDIM * NPIX;
  unsigned short* Out = Out0 + (size_t)b * C2 * NPIX;
  const int px0 = blockIdx.x * 128;
  __shared__ __align__(16) char smem[67584];
  short* sA = (short*)smem;              // 384*64 (49152 B)
  short* sB = (short*)(smem + 49152);    // 128*72 (18432 B)
  const int t = threadIdx.x;
  const int lane = t & 63;
  const int wid = t >> 6;          // 0..7 -> oc rows wid*48..+47
  const int cpp = t & 31;          // channel pair 0..31 (64 ch per chunk)
  const int pg = t >> 5;           // 0..15 -> 8 px each
  const int l15 = lane & 15;
  const int l4 = lane >> 4;

  f32x4 acc[3][8];
#pragma unroll
  for (int mi = 0; mi < 3; ++mi)
#pragma unroll
    for (int ni = 0; ni < 8; ++ni) acc[mi][ni] = (f32x4){0.f, 0.f, 0.f, 0.f};

  for (int k0 = 0; k0 < CDIM; k0 += 64) {
    // A stage: 384 rows x 8 chunks = 3072 chunks, 6 issues x 512 lanes.
#pragma unroll
    for (int i = 0; i < 6; ++i) {
      int g = i * 512 + t;
      int row = g >> 3, ck = g & 7;
      gload_lds16(W + (size_t)row * CDIM + k0 + ((ck ^ (row & 7)) * 8),
                  (char*)sA + ((size_t)i * 512 + (t & ~63)) * 16);
    }
    // B stage: fused f32->bf16 transpose, 2 rows x 8 px per thread.
    {
      const float* xp = X + (size_t)(k0 + 2 * cpp) * NPIX + px0 + 8 * pg;
      float4 a0 = *(const float4*)xp;
      float4 a1 = *(const float4*)(xp + 4);
      float4 b0 = *(const float4*)(xp + NPIX);
      float4 b1 = *(const float4*)(xp + NPIX + 4);
      float av[8] = {a0.x, a0.y, a0.z, a0.w, a1.x, a1.y, a1.z, a1.w};
      float bv[8] = {b0.x, b0.y, b0.z, b0.w, b1.x, b1.y, b1.z, b1.w};
#pragma unroll
      for (int i = 0; i < 8; ++i) {
        unsigned d = (unsigned)f2bf(av[i]) | ((unsigned)f2bf(bv[i]) << 16);
        *(unsigned*)&sB[(8 * pg + i) * 72 + 2 * cpp] = d;
      }
    }
    asm volatile("s_waitcnt vmcnt(0)");
    __syncthreads();
#pragma unroll
    for (int kk = 0; kk < 2; ++kk) {
      short8 af[3], bf[8];
#pragma unroll
      for (int mi = 0; mi < 3; ++mi) {
        int row = wid * 48 + mi * 16 + l15;
        af[mi] = *(const short8*)&sA[row * 64 +
                                     (((kk * 4 + l4) ^ (row & 7)) * 8)];
      }
#pragma unroll
      for (int ni = 0; ni < 8; ++ni)
        bf[ni] = *(const short8*)&sB[(ni * 16 + l15) * 72 + (kk * 4 + l4) * 8];
#pragma unroll
      for (int mi = 0; mi < 3; ++mi)
#pragma unroll
        for (int ni = 0; ni < 8; ++ni)
          acc[mi][ni] = __builtin_amdgcn_mfma_f32_16x16x32_bf16(
              af[mi], bf[ni], acc[mi][ni], 0, 0, 0);
    }
    __syncthreads();
  }
  // Epilogue: per-wave zone (16 oc x 128 px, stride 136), short8 stores.
  short* zones = (short*)smem;
  short* zone = zones + wid * 2176;   // 8 * 2176 shorts = 34816 B <= 67584
#pragma unroll
  for (int mi = 0; mi < 3; ++mi) {
#pragma unroll
    for (int ni = 0; ni < 8; ++ni)
#pragma unroll
      for (int rg = 0; rg < 4; ++rg)
        zone[(l4 * 4 + rg) * 136 + ni * 16 + l15] =
            (short)f2bf(acc[mi][ni][rg]);
    asm volatile("s_waitcnt lgkmcnt(0)" ::: "memory");
    __builtin_amdgcn_sched_barrier(0);
#pragma unroll
    for (int it = 0; it < 4; ++it) {
      int e = it * 64 + lane;
      int ol = e >> 4, pxg = e & 15;
      short8 vv = *(const short8*)&zone[ol * 136 + pxg * 8];
      *(short8*)&Out[(size_t)(wid * 48 + mi * 16 + ol) * NPIX + px0 + pxg * 8] = vv;
    }
    asm volatile("s_waitcnt lgkmcnt(0)" ::: "memory");
    __builtin_amdgcn_sched_barrier(0);
  }
}

// ---------------------------------------------------------------------------
// v 1x1 conv as MFMA v5: T14 software pipeline (round-16 proven).
// ---------------------------------------------------------------------------
__global__ __launch_bounds__(256, 4) void v_mfma_kernel(
    const float* __restrict__ Y0, const unsigned short* __restrict__ W,
    unsigned short* __restrict__ Xt0) {
  const int b = blockIdx.y;
  const float* Y = Y0 + (size_t)b * CDIM * NPIX;
  unsigned short* Xt = Xt0 + (size_t)b * XTROWS * CDIM;
  const int px0 = blockIdx.x * 64;
  const int h = px0 >> 8;
  const int w0 = px0 & 255;
  __shared__ __align__(16) char smem[34816];
  const int t = threadIdx.x;
  const int lane = t & 63;
  const int wid = t >> 6;
  const int cp = t & 15;
  const int pg = t >> 4;
  const int l15 = lane & 15;
  const int l4 = lane >> 4;

  f32x4 acc[12];
#pragma unroll
  for (int ni = 0; ni < 12; ++ni) acc[ni] = (f32x4){0.f, 0.f, 0.f, 0.f};

#define SXB(p) ((short*)(smem + (p) * 5120))
#define SWB(p) ((short*)(smem + 10240 + (p) * 12288))

#define STAGE_W(k0_, p_)                                                     \
  {                                                                          \
    _Pragma("unroll")                                                        \
    for (int i = 0; i < 3; ++i) {                                            \
      int e = i * 256 + t;                                                   \
      int oc = e >> 2, kg = e & 3;                                           \
      gload_lds16(W + (size_t)oc * CDIM + (k0_) + (kg ^ f4(oc)) * 8,         \
                  (char*)SWB(p_) + ((size_t)i * 256 + (t & ~63)) * 16);      \
    }                                                                        \
  }

  float4 ya, yb;
#define LOAD_Y(k0_)                                                          \
  {                                                                          \
    const float* xp = Y + (size_t)((k0_) + 2 * cp) * NPIX + px0 + 4 * pg;    \
    ya = *(const float4*)xp;                                                 \
    yb = *(const float4*)(xp + NPIX);                                        \
  }
#define WRITE_X(p_)                                                          \
  {                                                                          \
    float av[4] = {ya.x, ya.y, ya.z, ya.w};                                  \
    float bv[4] = {yb.x, yb.y, yb.z, yb.w};                                  \
    short* sx = SXB(p_);                                                     \
    _Pragma("unroll")                                                        \
    for (int i = 0; i < 4; ++i) {                                            \
      unsigned d = (unsigned)f2bf(av[i]) | ((unsigned)f2bf(bv[i]) << 16);    \
      *(unsigned*)&sx[(4 * pg + i) * 40 + 2 * cp] = d;                       \
    }                                                                        \
  }

  LOAD_Y(0);
  STAGE_W(0, 0);
  WRITE_X(0);
  asm volatile("s_waitcnt vmcnt(0)" ::: "memory");
  __syncthreads();

  for (int k = 0; k < 6; ++k) {
    const int p = k & 1;
    if (k < 5) {
      LOAD_Y((k + 1) * 32);
      STAGE_W((k + 1) * 32, p ^ 1);
    }
    {
      short* sx = SXB(p);
      short* sw = SWB(p);
      short8 af = *(const short8*)&sx[(wid * 16 + l15) * 40 + l4 * 8];
      short8 bf[12];
#pragma unroll
      for (int ni = 0; ni < 12; ++ni) {
        int row = ni * 16 + l15;
        bf[ni] = *(const short8*)&sw[row * 32 + (l4 ^ f4(row)) * 8];
      }
#pragma unroll
      for (int ni = 0; ni < 12; ++ni)
        acc[ni] = __builtin_amdgcn_mfma_f32_16x16x32_bf16(af, bf[ni], acc[ni],
                                                          0, 0, 0);
    }
    if (k < 5) WRITE_X(p ^ 1);
    asm volatile("s_waitcnt vmcnt(0)" ::: "memory");
    __syncthreads();
  }
#undef STAGE_W
#undef LOAD_Y
#undef WRITE_X
#undef SXB
#undef SWB

  // Epilogue: 2 oc-half passes of [16 px][104] zone overlaying sW region.
  short* zone = (short*)(smem + 10240) + wid * (16 * 104);
#pragma unroll
  for (int oh = 0; oh < 2; ++oh) {
#pragma unroll
    for (int ni = 0; ni < 6; ++ni)
#pragma unroll
      for (int rg = 0; rg < 4; ++rg)
        zone[(l4 * 4 + rg) * 104 + ni * 16 + l15] =
            (short)f2bf(acc[oh * 6 + ni][rg]);
    asm volatile("s_waitcnt lgkmcnt(0)" ::: "memory");
    __builtin_amdgcn_sched_barrier(0);
#pragma unroll
    for (int it = 0; it < 3; ++it) {
      int e = it * 64 + lane;
      int pl = e / 12, cg = e % 12;
      short8 vv = *(const short8*)&zone[pl * 104 + cg * 8];
      size_t xrow = (size_t)(h + 1) * PROW + (w0 + wid * 16 + pl + 1);
      *(short8*)&Xt[xrow * CDIM + oh * 96 + cg * 8] = vv;
    }
    asm volatile("s_waitcnt lgkmcnt(0)" ::: "memory");
    __builtin_amdgcn_sched_barrier(0);
  }
}

// ---------------------------------------------------------------------------
// Zero the padded border of both Xt buffers (blockIdx.y = batch).
// ---------------------------------------------------------------------------
__global__ __launch_bounds__(128) void border_zero_kernel(
    unsigned short* __restrict__ Xt0) {
  unsigned short* Xt = Xt0 + (size_t)blockIdx.y * XTROWS * CDIM;
  int pos = blockIdx.x;                 // 0..1027
  size_t row;
  if (pos < 258) row = pos;                                   // padded row 0
  else if (pos < 516) row = (size_t)257 * PROW + (pos - 258); // padded row 257
  else { int i = pos - 516; row = (size_t)(1 + (i >> 1)) * PROW + ((i & 1) ? 257 : 0); }
  unsigned* p = (unsigned*)(Xt + row * CDIM);
  if (threadIdx.x < 96) p[threadIdx.x] = 0;
}

// ---------------------------------------------------------------------------
// FUSED depthwise-3x3 + sumsq + Gram-MFMA. Grid (64, 4 heads, 2 batches).
// 4 image rows per block (wave = 1 full row, 8 chunks of 32 px):
// halo = 6 rows read per 4 computed (1.5x). XCD band swizzle:
// blk=(braw&7)*8+braw>>3 -> XCD gets 32 contiguous rows. 64 partials/(b,h).
// ---------------------------------------------------------------------------
__global__ __launch_bounds__(256) void dwgram_kernel(
    const unsigned short* __restrict__ qkb0, const float* __restrict__ dw,
    float* __restrict__ gpart, float* __restrict__ ssp) {
  const int head = blockIdx.y;
  const int b = blockIdx.z;
  const int bh = b * HEADS + head;
  const unsigned short* qkb = qkb0 + (size_t)b * C2 * NPIX;
  float* gpart_b = gpart + (size_t)bh * 64 * (HD * HD);
  float* ssp_b = ssp + (size_t)bh * 64 * 96;
  const int braw = blockIdx.x;          // 0..63
  const int blk = (braw & 7) * 8 + (braw >> 3);   // XCD-contiguous band
  const int t = threadIdx.x;
  const int lane = t & 63;
  const int wid = t >> 6;

  __shared__ __align__(16) char smem[38400];
  short* zone = (short*)smem + wid * (96 * 40);   // 4 x 7680 B = 30720 B

  const int qrow0 = HD * head, krow0 = CDIM + HD * head;
  const int p0 = (lane & 1) * 16;       // px half within 32-chunk
  const int c0 = (lane >> 1) * 3;       // 3 channels per lane-pair

  float wr[3][9];
#pragma unroll
  for (int j = 0; j < 3; ++j) {
    int ch = c0 + j;
    int srow = (ch < HD) ? (qrow0 + ch) : (krow0 + ch - HD);
#pragma unroll
    for (int i = 0; i < 9; ++i) wr[j][i] = dw[srow * 9 + i];
  }

  f32x4 acc[3][3];
#pragma unroll
  for (int mi = 0; mi < 3; ++mi)
#pragma unroll
    for (int nj = 0; nj < 3; ++nj) acc[mi][nj] = (f32x4){0.f, 0.f, 0.f, 0.f};
  float ss[3] = {0.f, 0.f, 0.f};

  const int hr = blk * 4 + wid;         // this wave's image row (0..255)
  for (int s = 0; s < 8; ++s) {
    const int cl = s * 32 + p0;
#pragma unroll
    for (int j = 0; j < 3; ++j) {
      int ch = c0 + j;
      int srow = (ch < HD) ? (qrow0 + ch) : (krow0 + ch - HD);
      const unsigned short* ip = qkb + (size_t)srow * NPIX;
      float win[3][18];
#pragma unroll
      for (int r = 0; r < 3; ++r) {
        int ir = hr - 1 + r;
        if ((unsigned)ir < 256u) {
          const unsigned short* rp = ip + ir * 256 + cl;
          short8 v0 = *(const short8*)rp;
          short8 v1 = *(const short8*)(rp + 8);
#pragma unroll
          for (int q = 0; q < 8; ++q) {
            win[r][1 + q] = bf2f((unsigned short)v0[q]);
            win[r][9 + q] = bf2f((unsigned short)v1[q]);
          }
          win[r][0]  = (cl > 0)        ? bf2f(rp[-1]) : 0.f;
          win[r][17] = (cl + 16 < 256) ? bf2f(rp[16]) : 0.f;
        } else {
#pragma unroll
          for (int q = 0; q < 18; ++q) win[r][q] = 0.f;
        }
      }
      unsigned pk[8];
#pragma unroll
      for (int p = 0; p < 16; ++p) {
        float sacc = 0.f;
#pragma unroll
        for (int r = 0; r < 3; ++r)
#pragma unroll
          for (int c = 0; c < 3; ++c) sacc += wr[j][r * 3 + c] * win[r][p + c];
        ss[j] += sacc * sacc;
        unsigned short bb = f2bf(sacc);
        if (p & 1) pk[p >> 1] |= ((unsigned)bb << 16);
        else       pk[p >> 1] = bb;
      }
      unsigned* zp = (unsigned*)&zone[ch * 40 + p0];
#pragma unroll
      for (int q = 0; q < 8; ++q) zp[q] = pk[q];
    }
    asm volatile("s_waitcnt lgkmcnt(0)" ::: "memory");
    __builtin_amdgcn_sched_barrier(0);
    short8 qf[3], kf[3];
#pragma unroll
    for (int mi = 0; mi < 3; ++mi)
      qf[mi] = *(const short8*)&zone[(mi * 16 + (lane & 15)) * 40 +
                                     (lane >> 4) * 8];
#pragma unroll
    for (int nj = 0; nj < 3; ++nj)
      kf[nj] = *(const short8*)&zone[(HD + nj * 16 + (lane & 15)) * 40 +
                                     (lane >> 4) * 8];
#pragma unroll
    for (int mi = 0; mi < 3; ++mi)
#pragma unroll
      for (int nj = 0; nj < 3; ++nj)
        acc[mi][nj] = __builtin_amdgcn_mfma_f32_16x16x32_bf16(
            qf[mi], kf[nj], acc[mi][nj], 0, 0, 0);
    asm volatile("s_waitcnt lgkmcnt(0)" ::: "memory");
    __builtin_amdgcn_sched_barrier(0);
  }
  // ---- block-level reduce: zones dead, overlay reduction buffers ----
  __syncthreads();
  float* red   = (float*)smem;            // [4][2304]
  float* ssred = (float*)(smem + 36864);  // [4][96]
#pragma unroll
  for (int mi = 0; mi < 3; ++mi)
#pragma unroll
    for (int nj = 0; nj < 3; ++nj) {
      int kj = nj * 16 + (lane & 15);
#pragma unroll
      for (int rg = 0; rg < 4; ++rg) {
        int qi = mi * 16 + (lane >> 4) * 4 + rg;
        red[wid * 2304 + qi * HD + kj] = acc[mi][nj][rg];
      }
    }
#pragma unroll
  for (int j = 0; j < 3; ++j) {
    float sj = ss[j] + __shfl_xor(ss[j], 1);
    if ((lane & 1) == 0) ssred[wid * 96 + c0 + j] = sj;
  }
  __syncthreads();
  float* gp = gpart_b + (size_t)blk * (HD * HD);
  for (int e = t; e < HD * HD; e += 256)
    gp[e] = red[e] + red[2304 + e] + red[4608 + e] + red[6912 + e];
  if (t < 96)
    ssp_b[(size_t)blk * 96 + t] =
        ssred[t] + ssred[96 + t] + ssred[192 + t] + ssred[288 + t];
}

// ---------------------------------------------------------------------------
// parallel small-kernel chain: normred / gramred / softmax / buildM.
// ---------------------------------------------------------------------------
__global__ __launch_bounds__(64) void normred_kernel(
    const float* __restrict__ ssp, float* __restrict__ norms) {
  int idx = blockIdx.x;                 // 768 = 8 bh x 96 ch
  int bh = idx / 96, ch = idx % 96;
  int l = threadIdx.x;                  // 64
  float s = ssp[((size_t)bh * 64 + l) * 96 + ch];
#pragma unroll
  for (int off = 32; off; off >>= 1) s += __shfl_down(s, off);
  if (l == 0) {
    int b = bh >> 2, hh = bh & 3;
    int g = b * C2 + (ch < HD ? hh * HD + ch : CDIM + hh * HD + ch - HD);
    norms[g] = sqrtf(s);
  }
}

__global__ __launch_bounds__(256) void gramred_kernel(
    const float* __restrict__ part, float* __restrict__ logits) {
  int ij = blockIdx.x * 256 + threadIdx.x;
  int bh = blockIdx.y;
  if (ij >= HD * HD) return;
  const float* pp = part + (size_t)bh * 64 * (HD * HD);
  float s = 0.f;
  for (int sp = 0; sp < 64; ++sp) s += pp[(size_t)sp * (HD * HD) + ij];
  logits[(size_t)bh * (HD * HD) + ij] = s;
}

__global__ __launch_bounds__(64) void softmax_kernel(
    float* __restrict__ logits, const float* __restrict__ norms,
    const float* __restrict__ temperature) {
  int hh = blockIdx.x, b = blockIdx.y;
  int i = threadIdx.x;
  if (i >= HD) return;
  const float eps = 1e-12f;
  float temp = temperature[hh];
  float nq = fmaxf(norms[b * C2 + HD * hh + i], eps);
  float* row = logits + (((size_t)b * HEADS + hh) * HD + i) * HD;
  float vals[48];
  float mx = -1e30f;
#pragma unroll
  for (int j = 0; j < HD; ++j) {
    float nk = fmaxf(norms[b * C2 + CDIM + HD * hh + j], eps);
    float v = row[j] / (nq * nk) * temp;
    vals[j] = v;
    mx = fmaxf(mx, v);
  }
  float sum = 0.f;
#pragma unroll
  for (int j = 0; j < HD; ++j) {
    vals[j] = expf(vals[j] - mx);
    sum += vals[j];
  }
  float inv = 1.f / sum;
#pragma unroll
  for (int j = 0; j < HD; ++j) row[j] = vals[j] * inv;
}

__global__ __launch_bounds__(256) void buildM_kernel(
    const float* __restrict__ attn, const float* __restrict__ projw,
    float* __restrict__ M) {
  int idx = blockIdx.x * 256 + threadIdx.x;
  if (idx >= 2 * CDIM * CDIM) return;
  int d = idx % CDIM;
  int oc = (idx / CDIM) % CDIM;
  int b = idx / (CDIM * CDIM);
  int hh = d / HD, dd = d % HD;
  const float* arow = attn + ((size_t)b * HEADS + hh) * HD * HD;
  float s = 0.f;
#pragma unroll
  for (int c = 0; c < HD; ++c)
    s += projw[oc * CDIM + HD * hh + c] * arow[c * HD + dd];
  M[idx] = s;
}

// ---------------------------------------------------------------------------
// Wb[b][tap][oc][ic] (bf16) = sum_d M[b][oc][d] * Wv[d][ic][tap]
// ---------------------------------------------------------------------------
__global__ __launch_bounds__(256) void wtrans_kernel(
    const float* __restrict__ M, const float* __restrict__ Wv,
    unsigned short* __restrict__ Wb) {
  const int ocb = blockIdx.x * 4;
  const int ec0 = blockIdx.y * 432;
  const int b = blockIdx.z;
  __shared__ float sM[4][CDIM];
  for (int i = threadIdx.x; i < 4 * CDIM; i += 256)
    sM[i / CDIM][i % CDIM] =
        M[((size_t)b * CDIM + ocb + i / CDIM) * CDIM + (i % CDIM)];
  __syncthreads();
  for (int e = ec0 + threadIdx.x; e < ec0 + 432; e += 256) {
    float a0 = 0.f, a1 = 0.f, a2 = 0.f, a3 = 0.f;
#pragma unroll 4
    for (int d = 0; d < CDIM; ++d) {
      float wv = Wv[(size_t)d * (CDIM * 9) + e];
      a0 += sM[0][d] * wv; a1 += sM[1][d] * wv;
      a2 += sM[2][d] * wv; a3 += sM[3][d] * wv;
    }
    int ic = e / 9, tap = e % 9;
    size_t base = (((size_t)b * 9 + tap) * CDIM) * CDIM + ic;
    Wb[base + (size_t)(ocb + 0) * CDIM] = f2bf(a0);
    Wb[base + (size_t)(ocb + 1) * CDIM] = f2bf(a1);
    Wb[base + (size_t)(ocb + 2) * CDIM] = f2bf(a2);
    Wb[base + (size_t)(ocb + 3) * CDIM] = f2bf(a3);
  }
}

// ---------------------------------------------------------------------------
// MFMA conv3x3 v8: r-major dedup (18 stages), A consumed into registers,
// single-buffered sA: LDS 45.3 KB -> 3 blocks/CU. Batch-merged grid (768,2):
// x-major dispatch sends all 768 b=0 blocks (one full residency round)
// before b=1 -> L2 band locality preserved, launch gap eliminated.
// ---------------------------------------------------------------------------
__global__ __launch_bounds__(256, 3) void conv3x3_mfma_kernel(
    const unsigned short* __restrict__ XtAll,  // [2][XTROWS][192] bf16
    const unsigned short* __restrict__ WbAll,  // [2][9][192][192] bf16
    float* __restrict__ outAll) {
  const int bb = blockIdx.y;
  const unsigned short* Xt = XtAll + (size_t)bb * XTROWS * CDIM;
  const unsigned short* Wb = WbAll + (size_t)bb * 9 * CDIM * CDIM;
  float* out = outAll + (size_t)bb * CDIM * NPIX;

  const int d = blockIdx.x;              // 768
  const int xcd = d & 7;
  const int j = d >> 3;                  // 0..95
  const int h = xcd * 32 + j / 3;        // image row 0..255
  const int oc0 = (j % 3) * 64;

  __shared__ __align__(16) short sA[3 * 64 * 32];      // 12,288 B (single buf)
  __shared__ __align__(16) short sB[2][258 * 32];      // 2 x 16,512 B

  const int t = threadIdx.x;
  const int lane = t & 63;
  const int wid = t >> 6;                // px quarter (64 px each)
  const int l15 = lane & 15;
  const int l4 = lane >> 4;

  f32x4 acc[4][4];
#pragma unroll
  for (int mi = 0; mi < 4; ++mi)
#pragma unroll
    for (int ni = 0; ni < 4; ++ni) acc[mi][ni] = (f32x4){0.f, 0.f, 0.f, 0.f};

  // A: 3 taps x 64 oc x 32 ic = 768 chunks = 3 uniform issues.
#define STAGE_A(sidx)                                                        \
  {                                                                          \
    const int ra_ = (sidx) / 6;                                              \
    const int ica_ = ((sidx) % 6) * 32;                                      \
    _Pragma("unroll")                                                        \
    for (int i = 0; i < 3; ++i) {                                            \
      int g = i * 256 + t;                                                   \
      int row = g >> 2, ck = g & 3;                                          \
      int tap = row >> 6, oc = row & 63;                                     \
      gload_lds16(Wb + ((size_t)(ra_ * 3 + tap) * CDIM + oc0 + oc) * CDIM +  \
                      ica_ + (ck ^ f4(row)) * 8,                             \
                  (char*)sA + (size_t)(i * 256 + wid * 64) * 16);            \
    }                                                                        \
  }
  // B: 258 px-rows x 32 ic = 1032 chunks = 4 full + 1 partial issue.
#define STAGE_B(sidx, bi)                                                    \
  {                                                                          \
    const int rs_ = (sidx) / 6;                                              \
    const int ics_ = ((sidx) % 6) * 32;                                      \
    const unsigned short* bsrc =                                             \
        Xt + (size_t)(h + rs_) * PROW * CDIM + ics_;                         \
    _Pragma("unroll")                                                        \
    for (int i = 0; i < 4; ++i) {                                            \
      int g = i * 256 + t;                                                   \
      int row = g >> 2, ck = g & 3;                                          \
      gload_lds16(bsrc + (size_t)row * CDIM + (ck ^ f4(row)) * 8,            \
                  (char*)sB[bi] + (size_t)(i * 256 + wid * 64) * 16);        \
    }                                                                        \
    { int g = 1024 + wid * 2 + lane;                                         \
      int row = g >> 2, ck = g & 3;                                          \
      if (lane < 2)                                                          \
        gload_lds16(bsrc + (size_t)row * CDIM + (ck ^ f4(row)) * 8,          \
                    (char*)sB[bi] + (size_t)(1024 + wid * 2) * 16);          \
    }                                                                        \
  }

  STAGE_A(0);
  STAGE_B(0, 0);
  asm volatile("s_waitcnt vmcnt(0)" ::: "memory");
  __syncthreads();

  int cur = 0;
  for (int s = 0; s < 18; ++s) {
    // consume A[s] into registers (12 ds_read_b128, conflict-free)
    short8 af_[3][4];
#pragma unroll
    for (int c = 0; c < 3; ++c)
#pragma unroll
      for (int mi = 0; mi < 4; ++mi) {
        int row = c * 64 + mi * 16 + l15;
        af_[c][mi] = *(const short8*)&sA[row * 32 + (l4 ^ f4(row)) * 8];
      }
    __syncthreads();                 // all waves done reading sA
    if (s < 17) {
      STAGE_A(s + 1);                // safe: sA consumed
      STAGE_B(s + 1, cur ^ 1);
    }
#pragma unroll
    for (int c = 0; c < 3; ++c) {
      short8 bf[4];
#pragma unroll
      for (int ni = 0; ni < 4; ++ni) {
        int row = wid * 64 + ni * 16 + l15 + c;   // padded px index
        bf[ni] = *(const short8*)&sB[cur][row * 32 + (l4 ^ f4(row)) * 8];
      }
#pragma unroll
      for (int mi = 0; mi < 4; ++mi)
#pragma unroll
        for (int ni = 0; ni < 4; ++ni)
          acc[mi][ni] = __builtin_amdgcn_mfma_f32_16x16x32_bf16(
              af_[c][mi], bf[ni], acc[mi][ni], 0, 0, 0);
    }
    asm volatile("s_waitcnt vmcnt(0)" ::: "memory");
    __syncthreads();                 // A[s+1], B[s+1] landed & visible
    cur ^= 1;
  }
#undef STAGE_A
#undef STAGE_B
  // D: col=lane&15 (px), row=(lane>>4)*4+reg (oc)
#pragma unroll
  for (int mi = 0; mi < 4; ++mi) {
    int ocl = oc0 + mi * 16 + l4 * 4;
#pragma unroll
    for (int ni = 0; ni < 4; ++ni) {
      int wloc = wid * 64 + ni * 16 + l15;
#pragma unroll
      for (int rg = 0; rg < 4; ++rg)
        out[(size_t)(ocl + rg) * NPIX + h * 256 + wloc] = acc[mi][ni][rg];
    }
  }
}

// ---------------------------------------------------------------------------
extern "C" void kernel_launch(void* const* d_in, const int* in_sizes, int n_in,
                              void* d_out, int out_size, void* d_ws, size_t ws_size,
                              hipStream_t stream) {
  const float* x          = (const float*)d_in[0];
  const float* y          = (const float*)d_in[1];
  const float* qk_w       = (const float*)d_in[2];
  const float* qk_dw_w    = (const float*)d_in[3];
  const float* v_w        = (const float*)d_in[4];
  const float* v_dw_w     = (const float*)d_in[5];
  const float* proj_w     = (const float*)d_in[6];
  const float* temperature= (const float*)d_in[7];
  float* out = (float*)d_out;

  // Workspace layout. Peak ~110 MB (ws ~400 MB per harness poison size).
  unsigned short* qkb = (unsigned short*)d_ws;          // 2 x 384 x 65536 bf16
  unsigned short* XtA = qkb;                            // overlay (qkb dead in v path)
  float* gpart  = (float*)(qkb + (size_t)2 * C2 * NPIX);  // [8][64][2304]
  float* ssp    = gpart + (size_t)8 * 64 * HD * HD;     // [8][64][96]
  float* norms  = ssp + (size_t)8 * 64 * 96;            // 768
  float* logits = norms + 768;                          // 4608
  float* M      = logits + 2 * HEADS * HD * HD;         // 73728
  unsigned short* wqk = (unsigned short*)(M + 2 * CDIM * CDIM);
  unsigned short* wv  = wqk + C2 * CDIM;
  unsigned short* Wb  = wv + CDIM * CDIM;               // 2*9*192*192 bf16
  size_t needB = (size_t)((char*)(Wb + (size_t)2 * 9 * CDIM * CDIM) - (char*)d_ws);
  if (ws_size < needB) return;

  castw_kernel<<<dim3(288), dim3(256), 0, stream>>>(qk_w, v_w, wqk, wv);

  // ---- qk path, batch-merged: 1x1 MFMA then fused dw+sumsq+gram ----
  qk_mfma_kernel<<<dim3(512, 2), dim3(512), 0, stream>>>(x, wqk, qkb);
  dwgram_kernel<<<dim3(64, HEADS, 2), dim3(256), 0, stream>>>(
      qkb, qk_dw_w, gpart, ssp);
  normred_kernel<<<dim3(768), dim3(64), 0, stream>>>(ssp, norms);
  gramred_kernel<<<dim3(9, 8), dim3(256), 0, stream>>>(gpart, logits);
  softmax_kernel<<<dim3(4, 2), dim3(64), 0, stream>>>(logits, norms, temperature);
  buildM_kernel<<<dim3(288), dim3(256), 0, stream>>>(logits, proj_w, M);
  wtrans_kernel<<<dim3(48, 4, 2), dim3(256), 0, stream>>>(M, v_dw_w, Wb);

  // ---- v path (XtA overlays qkb, now dead) ----
  border_zero_kernel<<<dim3(1028, 2), dim3(128), 0, stream>>>(XtA);
  v_mfma_kernel<<<dim3(1024, 2), dim3(256), 0, stream>>>(y, wv, XtA);
  conv3x3_mfma_kernel<<<dim3(768, 2), dim3(256), 0, stream>>>(XtA, Wb, out);
}